// Round 6
// baseline (219.464 us; speedup 1.0000x reference)
//
#include <hip/hip_runtime.h>
#include <hip/hip_bf16.h>

#define B_ 16
#define S_ 1024
#define D_ 512
#define H_ 8
#define DH_ 64

typedef __attribute__((ext_vector_type(8))) short bf16x8;
typedef __attribute__((ext_vector_type(4))) short bf16x4;
typedef __attribute__((ext_vector_type(4))) float f32x4;
typedef __attribute__((ext_vector_type(16))) float f32x16;

__device__ __forceinline__ short f2bf(float f) {
    __hip_bfloat16 h = __float2bfloat16(f);
    return *reinterpret_cast<short*>(&h);
}
__device__ __forceinline__ unsigned pack_bf2(float lo, float hi) {
    unsigned a = (unsigned)(unsigned short)f2bf(lo);
    unsigned b = (unsigned)(unsigned short)f2bf(hi);
    return a | (b << 16);
}
__device__ __forceinline__ void gload16(const void* g, void* l) {
    __builtin_amdgcn_global_load_lds(
        (const __attribute__((address_space(1))) unsigned int*)g,
        (__attribute__((address_space(3))) unsigned int*)l, 16, 0, 0);
}

// ---------------------------------------------------------------------------
// prep_w: convert the 5 weight matrices (512x512 f32 each) to bf16 in ws.
// Order: M, Wq (pre-scaled by 0.125*log2e), Wk, Wv, Wo. 8 elems/thread.
// Wq/Wk/Wv end up contiguous -> fused QKV GEMM weight (1536x512).
// ---------------------------------------------------------------------------
__global__ __launch_bounds__(256) void prep_w(
    const float* __restrict__ M, const float* __restrict__ Wq,
    const float* __restrict__ Wk, const float* __restrict__ Wv,
    const float* __restrict__ Wo, __hip_bfloat16* __restrict__ wb)
{
    const int gid = blockIdx.x * 256 + threadIdx.x;
    const int e8 = gid * 8;
    const int w = e8 >> 18;              // 262144 elems per weight
    const int off = e8 & 262143;
    const float* src = (w == 0) ? M : (w == 1) ? Wq : (w == 2) ? Wk
                      : (w == 3) ? Wv : Wo;
    const float scale = (w == 1) ? 0.18033688011112042f : 1.0f;
    const float4 f0 = *reinterpret_cast<const float4*>(src + off);
    const float4 f1 = *reinterpret_cast<const float4*>(src + off + 4);
    union { short s[8]; bf16x8 v; } r;
    r.s[0] = f2bf(f0.x * scale); r.s[1] = f2bf(f0.y * scale);
    r.s[2] = f2bf(f0.z * scale); r.s[3] = f2bf(f0.w * scale);
    r.s[4] = f2bf(f1.x * scale); r.s[5] = f2bf(f1.y * scale);
    r.s[6] = f2bf(f1.z * scale); r.s[7] = f2bf(f1.w * scale);
    *reinterpret_cast<bf16x8*>(wb + e8) = r.v;
}

// ---------------------------------------------------------------------------
// K1: conv1d(stride=pool) + bias + pos-emb + exact GELU + LayerNorm over D
//     -> n1 bf16, layout (B*S, 512) row-major
// ---------------------------------------------------------------------------
__global__ __launch_bounds__(256) void k1_conv_gelu_ln(
    const float* __restrict__ ts, const float* __restrict__ conv_w,
    const float* __restrict__ conv_b, const float* __restrict__ pe,
    const float* __restrict__ g1, const float* __restrict__ b1,
    __hip_bfloat16* __restrict__ n1)
{
    const int row = blockIdx.x;          // b*S + s
    const int b = row >> 10, s = row & 1023;
    const int t = threadIdx.x;
    const float4 x = *reinterpret_cast<const float4*>(ts + b * 4096 + s * 4);

    float a[2];
#pragma unroll
    for (int k = 0; k < 2; ++k) {
        const int d = t + k * 256;
        const float4 w = *reinterpret_cast<const float4*>(conv_w + d * 4);
        float v = x.x * w.x + x.y * w.y + x.z * w.z + x.w * w.w
                + conv_b[d] + pe[s * 512 + d];
        a[k] = 0.5f * v * (1.0f + erff(v * 0.70710678118654752f));
    }
    float sum = a[0] + a[1], sq = a[0] * a[0] + a[1] * a[1];
#pragma unroll
    for (int off = 32; off > 0; off >>= 1) {
        sum += __shfl_down(sum, off);
        sq  += __shfl_down(sq, off);
    }
    __shared__ float rs[4], rq[4];
    const int wv = t >> 6, ln = t & 63;
    if (ln == 0) { rs[wv] = sum; rq[wv] = sq; }
    __syncthreads();
    sum = rs[0] + rs[1] + rs[2] + rs[3];
    sq  = rq[0] + rq[1] + rq[2] + rq[3];
    const float mean = sum * (1.0f / 512.0f);
    const float var  = (sq - 512.0f * mean * mean) * (1.0f / 511.0f);
    const float rstd = rsqrtf(var + 1e-5f);
    const float gg = g1[s], bb = b1[s];
#pragma unroll
    for (int k = 0; k < 2; ++k) {
        const int d = t + k * 256;
        n1[(size_t)row * 512 + d] = __float2bfloat16(gg * ((a[k] - mean) * rstd) + bb);
    }
}

// ---------------------------------------------------------------------------
// GEMM: out[r][n] = sum_d A[r][d] * Wb[n][d]  (A bf16 16384x512, Wb bf16 Nx512)
// BM=128 BN=128 BK=64, 4 waves (2x2), each wave 64x64 = 4x4 16x16 frags.
// Staging via global_load_lds width=16 with pre-swizzled global source.
// MODE 0: += ts_emb[te[b]][n], write bf16 row-major (dense)
// MODE 3: += bo[n], write f32 row-major
// MODE 5: fused QKV (Wb = 1536x512): col w3=N>>9 -> q/k (B,H,S,DH) or vT (B,H,DH,S)
// ---------------------------------------------------------------------------
template<int MODE>
__global__ __launch_bounds__(256) void gemm_k(
    const __hip_bfloat16* __restrict__ A,
    const __hip_bfloat16* __restrict__ Wb,
    void* __restrict__ outp,
    const float* __restrict__ aux,
    const int* __restrict__ te)
{
    __shared__ char lA[128 * 128];   // 128 rows x 64 bf16, 16B-chunk swizzled
    __shared__ char lB[128 * 128];

    const int t = threadIdx.x;
    const int lane = t & 63;
    const int w = t >> 6;
    const int wm = w & 1, wn = w >> 1;
    const int Rb = blockIdx.x * 128;
    const int Nb = blockIdx.y * 128;
    const int g = lane >> 4, lr = lane & 15;
    const int lrow = lane >> 3;              // 0..7
    const int coff = ((lane & 7) ^ lrow) * 8;  // pre-swizzled element offset

    f32x4 acc[4][4];
#pragma unroll
    for (int i = 0; i < 4; ++i)
#pragma unroll
        for (int j = 0; j < 4; ++j) acc[i][j] = {0.f, 0.f, 0.f, 0.f};

    for (int kt = 0; kt < 8; ++kt) {
        const int k0 = kt * 64;
#pragma unroll
        for (int i = 0; i < 4; ++i) {
            const int r0 = w * 32 + i * 8;
            gload16(A + (size_t)(Rb + r0 + lrow) * 512 + k0 + coff, lA + r0 * 128);
        }
#pragma unroll
        for (int i = 0; i < 4; ++i) {
            const int r0 = w * 32 + i * 8;
            gload16(Wb + (size_t)(Nb + r0 + lrow) * 512 + k0 + coff, lB + r0 * 128);
        }
        __syncthreads();
#pragma unroll
        for (int kk = 0; kk < 2; ++kk) {
            bf16x8 af[4], bfv[4];
            const int ch = kk * 4 + g;
#pragma unroll
            for (int mt = 0; mt < 4; ++mt) {
                const int row = wm * 64 + mt * 16 + lr;
                af[mt] = *reinterpret_cast<const bf16x8*>(
                    lA + row * 128 + ((ch ^ (row & 7)) << 4));
            }
#pragma unroll
            for (int nt = 0; nt < 4; ++nt) {
                const int row = wn * 64 + nt * 16 + lr;
                bfv[nt] = *reinterpret_cast<const bf16x8*>(
                    lB + row * 128 + ((ch ^ (row & 7)) << 4));
            }
#pragma unroll
            for (int mt = 0; mt < 4; ++mt)
#pragma unroll
                for (int nt = 0; nt < 4; ++nt)
                    acc[mt][nt] = __builtin_amdgcn_mfma_f32_16x16x32_bf16(
                        af[mt], bfv[nt], acc[mt][nt], 0, 0, 0);
        }
        __syncthreads();
    }

    // epilogue
#pragma unroll
    for (int mt = 0; mt < 4; ++mt) {
#pragma unroll
        for (int nt = 0; nt < 4; ++nt) {
#pragma unroll
            for (int r = 0; r < 4; ++r) {
                const int R = Rb + wm * 64 + mt * 16 + 4 * g + r;
                const int N = Nb + wn * 64 + nt * 16 + lr;
                float v = acc[mt][nt][r];
                if (MODE == 0) {
                    const int b = R >> 10;
                    v += aux[(size_t)te[b] * 512 + N];
                    reinterpret_cast<__hip_bfloat16*>(outp)[(size_t)R * 512 + N] =
                        __float2bfloat16(v);
                } else if (MODE == 5) {
                    const int b = R >> 10, s = R & 1023;
                    const int w3 = N >> 9, Nl = N & 511;
                    const int h = Nl >> 6, c = Nl & 63;
                    __hip_bfloat16* base =
                        reinterpret_cast<__hip_bfloat16*>(outp) + (size_t)w3 * 8388608;
                    if (w3 == 2)
                        base[(((size_t)(b * 8 + h)) * 64 + c) * 1024 + s] =
                            __float2bfloat16(v);
                    else
                        base[(((size_t)(b * 8 + h)) * 1024 + s) * 64 + c] =
                            __float2bfloat16(v);
                } else {
                    reinterpret_cast<float*>(outp)[(size_t)R * 512 + N] = v + aux[N];
                }
            }
        }
    }
}

// ---------------------------------------------------------------------------
// Flash attention, transposed-score 32x32, dual balanced strips per wave,
// i-range SPLIT-2: each strip-pair handled by two half-waves (16-17 steps
// each), partials merged via LDS (online-softmax combine). 4096 waves.
// Q pre-scaled by 0.125*log2e (folded into Wq) -> exp2 softmax domain.
// ---------------------------------------------------------------------------
__device__ __forceinline__ void attn_step(
    const bf16x8 (&qf)[4], const bf16x8 (&kf)[4],
    const bf16x8& v00, const bf16x8& v01,
    const bf16x8& v10, const bf16x8& v11,
    const bool diag, const int l5, const int ln31,
    float& m, float& lsum, f32x16& o0, f32x16& o1)
{
    f32x16 sc;
#pragma unroll
    for (int r = 0; r < 16; ++r) sc[r] = 0.f;
#pragma unroll
    for (int kt = 0; kt < 4; ++kt)
        sc = __builtin_amdgcn_mfma_f32_32x32x16_bf16(qf[kt], kf[kt], sc, 0, 0, 0);

    float p[16];
    float mx = -3e38f;
    if (diag) {
#pragma unroll
        for (int r = 0; r < 16; ++r) {
            const int irow = (r & 3) + 8 * (r >> 2) + 4 * l5;
            const float v = (irow > ln31) ? -3e38f : sc[r];
            p[r] = v; mx = fmaxf(mx, v);
        }
    } else {
#pragma unroll
        for (int r = 0; r < 16; ++r) { p[r] = sc[r]; mx = fmaxf(mx, sc[r]); }
    }
    mx = fmaxf(mx, __shfl_xor(mx, 32));
    if (!__all(mx <= m + 8.0f)) {          // defer-max (T13), log2 domain
        const float mn = fmaxf(m, mx);
        const float alpha = exp2f(m - mn);
        m = mn; lsum *= alpha;
#pragma unroll
        for (int r = 0; r < 16; ++r) {
            const int jrow = (r & 3) + 8 * (r >> 2) + 4 * l5;
            const float ar = __shfl(alpha, jrow);
            o0[r] *= ar; o1[r] *= ar;
        }
    }
    float ps = 0.f;
#pragma unroll
    for (int r = 0; r < 16; ++r) { p[r] = exp2f(p[r] - m); ps += p[r]; }
    ps += __shfl_xor(ps, 32);
    lsum += ps;

    union { unsigned u[4]; bf16x8 v; } pa0, pa1;
    pa0.u[0] = pack_bf2(p[0],  p[1]);  pa0.u[1] = pack_bf2(p[2],  p[3]);
    pa0.u[2] = pack_bf2(p[4],  p[5]);  pa0.u[3] = pack_bf2(p[6],  p[7]);
    pa1.u[0] = pack_bf2(p[8],  p[9]);  pa1.u[1] = pack_bf2(p[10], p[11]);
    pa1.u[2] = pack_bf2(p[12], p[13]); pa1.u[3] = pack_bf2(p[14], p[15]);
    o0 = __builtin_amdgcn_mfma_f32_32x32x16_bf16(pa0.v, v00, o0, 0, 0, 0);
    o0 = __builtin_amdgcn_mfma_f32_32x32x16_bf16(pa1.v, v01, o0, 0, 0, 0);
    o1 = __builtin_amdgcn_mfma_f32_32x32x16_bf16(pa0.v, v10, o1, 0, 0, 0);
    o1 = __builtin_amdgcn_mfma_f32_32x32x16_bf16(pa1.v, v11, o1, 0, 0, 0);
}

__device__ __forceinline__ void merge_partial(
    float& m, float& lsum, f32x16& o0, f32x16& o1,
    const float* __restrict__ buf, const int l5)
{
    const float m1 = buf[32], l1 = buf[33];
    const float ms = fmaxf(m, m1);
    const float a0 = exp2f(m - ms);
    const float a1 = exp2f(m1 - ms);
    lsum = lsum * a0 + l1 * a1;
    m = ms;
#pragma unroll
    for (int r = 0; r < 16; ++r) {
        const int jrow = (r & 3) + 8 * (r >> 2) + 4 * l5;
        const float ar0 = __shfl(a0, jrow);
        const float ar1 = __shfl(a1, jrow);
        o0[r] = o0[r] * ar0 + buf[r]      * ar1;
        o1[r] = o1[r] * ar0 + buf[16 + r] * ar1;
    }
}

__device__ __forceinline__ void write_strip(
    __hip_bfloat16* __restrict__ dstbase, const int jw0,
    const f32x16& o0, const f32x16& o1, const float lsum,
    const int l5, const int ln31)
{
    const float linv = 1.0f / lsum;
#pragma unroll
    for (int r = 0; r < 16; ++r) {
        const int jrow = (r & 3) + 8 * (r >> 2) + 4 * l5;
        const float rinv = __shfl(linv, jrow);
        __hip_bfloat16* dst = dstbase + (size_t)(jw0 + jrow) * 512;
        dst[ln31]      = __float2bfloat16(o0[r] * rinv);
        dst[32 + ln31] = __float2bfloat16(o1[r] * rinv);
    }
}

__global__ __launch_bounds__(256, 2) void attn4_k(
    const __hip_bfloat16* __restrict__ Qm,   // (B,H,S,64), pre-scaled
    const __hip_bfloat16* __restrict__ Km,   // (B,H,S,64)
    const __hip_bfloat16* __restrict__ Vt,   // (B,H,64,S)
    __hip_bfloat16* __restrict__ cat)        // (B,S,512)
{
    __shared__ float mrg[2][2][64][34];      // [pair][chain][lane][o0,o1,m,l]

    const int t = threadIdx.x, lane = t & 63, w = t >> 6;
    const int l5 = lane >> 5, ln31 = lane & 31;
    const int bh = blockIdx.y;
    const int b = bh >> 3, h = bh & 7;
    const int q = w >> 1, half = w & 1;
    const int p = blockIdx.x * 2 + q;        // pair 0..15
    const int sA = p, sB = 31 - p;
    const int jA = sA * 32, jB = sB * 32;
    const int nA = sA + 1, nB = sB + 1;
    const int mp = (p >= 8) ? 8 : 16 - p;    // balanced split point
    const int lo = half ? mp : 0;
    const int hi = half ? nB : mp;

    const __hip_bfloat16* Qh = Qm + (size_t)bh * (S_ * 64);
    const __hip_bfloat16* Kh = Km + (size_t)bh * (S_ * 64);
    const __hip_bfloat16* Vh = Vt + (size_t)bh * (64 * S_);

    bf16x8 kfA[4], kfB[4];
#pragma unroll
    for (int kt = 0; kt < 4; ++kt) {
        kfA[kt] = *reinterpret_cast<const bf16x8*>(
            Kh + (size_t)(jA + ln31) * 64 + kt * 16 + l5 * 8);
        kfB[kt] = *reinterpret_cast<const bf16x8*>(
            Kh + (size_t)(jB + ln31) * 64 + kt * 16 + l5 * 8);
    }

    f32x16 oA0, oA1, oB0, oB1;
#pragma unroll
    for (int r = 0; r < 16; ++r) { oA0[r] = 0.f; oA1[r] = 0.f; oB0[r] = 0.f; oB1[r] = 0.f; }
    float mA = -3e38f, lsA = 0.f, mB = -3e38f, lsB = 0.f;

    const __hip_bfloat16* Vr0 = Vh + (size_t)ln31 * S_;
    const __hip_bfloat16* Vr1 = Vh + (size_t)(32 + ln31) * S_;

    for (int it = lo; it < hi; ++it) {
        const int i0 = it * 32;
        bf16x8 qf[4];
#pragma unroll
        for (int kt = 0; kt < 4; ++kt)
            qf[kt] = *reinterpret_cast<const bf16x8*>(
                Qh + (size_t)(i0 + ln31) * 64 + kt * 16 + l5 * 8);
        const int b0 = i0 + 4 * l5, b1 = i0 + 16 + 4 * l5;
        union u8 { bf16x4 h[2]; bf16x8 v; };
        u8 v00, v01, v10, v11;
        v00.h[0] = *reinterpret_cast<const bf16x4*>(Vr0 + b0);
        v00.h[1] = *reinterpret_cast<const bf16x4*>(Vr0 + b0 + 8);
        v01.h[0] = *reinterpret_cast<const bf16x4*>(Vr0 + b1);
        v01.h[1] = *reinterpret_cast<const bf16x4*>(Vr0 + b1 + 8);
        v10.h[0] = *reinterpret_cast<const bf16x4*>(Vr1 + b0);
        v10.h[1] = *reinterpret_cast<const bf16x4*>(Vr1 + b0 + 8);
        v11.h[0] = *reinterpret_cast<const bf16x4*>(Vr1 + b1);
        v11.h[1] = *reinterpret_cast<const bf16x4*>(Vr1 + b1 + 8);

        attn_step(qf, kfB, v00.v, v01.v, v10.v, v11.v,
                  it == nB - 1, l5, ln31, mB, lsB, oB0, oB1);
        if (it < nA)
            attn_step(qf, kfA, v00.v, v01.v, v10.v, v11.v,
                      it == nA - 1, l5, ln31, mA, lsA, oA0, oA1);
    }

    if (half) {
        float* bufB = &mrg[q][0][lane][0];
        float* bufA = &mrg[q][1][lane][0];
#pragma unroll
        for (int r = 0; r < 16; ++r) {
            bufB[r] = oB0[r]; bufB[16 + r] = oB1[r];
            bufA[r] = oA0[r]; bufA[16 + r] = oA1[r];
        }
        bufB[32] = mB; bufB[33] = lsB;
        bufA[32] = mA; bufA[33] = lsA;
    }
    __syncthreads();
    if (!half) {
        merge_partial(mB, lsB, oB0, oB1, &mrg[q][0][lane][0], l5);
        merge_partial(mA, lsA, oA0, oA1, &mrg[q][1][lane][0], l5);
        __hip_bfloat16* dstbase = cat + (size_t)b * 1024 * 512 + h * 64;
        write_strip(dstbase, jA, oA0, oA1, lsA, l5, ln31);
        write_strip(dstbase, jB, oB0, oB1, lsB, l5, ln31);
    }
}

// ---------------------------------------------------------------------------
// K5: residual (recompute conv) + LayerNorm over D, transposed store.
// Block = (b, 16-s chunk). LDS transpose so (B,D,S) f32 writes are 64B runs.
// ---------------------------------------------------------------------------
__global__ __launch_bounds__(256) void k5_res_ln(
    const float* __restrict__ outf,  // (B*S,512) = Wo@cat + bo
    const float* __restrict__ ts, const float* __restrict__ conv_w,
    const float* __restrict__ conv_b, const float* __restrict__ pe,
    const float* __restrict__ g2, const float* __restrict__ b2,
    float* __restrict__ out)         // (B,512,1024)
{
    __shared__ float tile[16 * 520];     // [sl][d], pad 520 to break banks
    const int blk = blockIdx.x;          // b*64 + schunk
    const int b = blk >> 6, s0 = (blk & 63) * 16;
    const int t = threadIdx.x;
    const int sl = t >> 4, c = t & 15;
    const int s = s0 + sl;

    const float4 x = *reinterpret_cast<const float4*>(ts + b * 4096 + s * 4);
    float vals[32];
    float sum = 0.f, sq = 0.f;
#pragma unroll
    for (int j = 0; j < 32; ++j) {
        const int d = c + 16 * j;
        const float4 wv = *reinterpret_cast<const float4*>(conv_w + d * 4);
        const float conv = x.x * wv.x + x.y * wv.y + x.z * wv.z + x.w * wv.w
                         + conv_b[d] + pe[s * 512 + d];
        const float a = outf[(size_t)(b * 1024 + s) * 512 + d] + conv;
        vals[j] = a; sum += a; sq += a * a;
    }
#pragma unroll
    for (int off = 1; off < 16; off <<= 1) {
        sum += __shfl_xor(sum, off);
        sq  += __shfl_xor(sq, off);
    }
    const float mean = sum * (1.0f / 512.0f);
    const float var  = (sq - 512.0f * mean * mean) * (1.0f / 511.0f);
    const float rstd = rsqrtf(var + 1e-5f);
    const float gg = g2[s], bb = b2[s];
#pragma unroll
    for (int j = 0; j < 32; ++j) {
        const int d = c + 16 * j;
        tile[sl * 520 + d] = gg * ((vals[j] - mean) * rstd) + bb;
    }
    __syncthreads();
#pragma unroll
    for (int q2 = 0; q2 < 2; ++q2) {
        const int d = t + q2 * 256;
        float buf[16];
#pragma unroll
        for (int sl2 = 0; sl2 < 16; ++sl2) buf[sl2] = tile[sl2 * 520 + d];
        float4* dst = reinterpret_cast<float4*>(
            out + ((size_t)b * 512 + d) * 1024 + s0);
        dst[0] = make_float4(buf[0],  buf[1],  buf[2],  buf[3]);
        dst[1] = make_float4(buf[4],  buf[5],  buf[6],  buf[7]);
        dst[2] = make_float4(buf[8],  buf[9],  buf[10], buf[11]);
        dst[3] = make_float4(buf[12], buf[13], buf[14], buf[15]);
    }
}

// ---------------------------------------------------------------------------
extern "C" void kernel_launch(void* const* d_in, const int* in_sizes, int n_in,
                              void* d_out, int out_size, void* d_ws, size_t ws_size,
                              hipStream_t stream)
{
    const float* ts     = (const float*)d_in[0];
    const int*   te     = (const int*)d_in[1];
    const float* conv_w = (const float*)d_in[2];
    const float* conv_b = (const float*)d_in[3];
    const float* pe     = (const float*)d_in[4];
    const float* ts_emb = (const float*)d_in[5];
    const float* g1     = (const float*)d_in[6];
    const float* b1     = (const float*)d_in[7];
    const float* M      = (const float*)d_in[8];
    const float* Wq     = (const float*)d_in[9];
    const float* Wk     = (const float*)d_in[10];
    const float* Wv     = (const float*)d_in[11];
    const float* Wo     = (const float*)d_in[12];
    const float* bo     = (const float*)d_in[13];
    const float* g2     = (const float*)d_in[14];
    const float* b2     = (const float*)d_in[15];

    char* ws = (char*)d_ws;
    __hip_bfloat16* wb    = (__hip_bfloat16*)(ws);                 // 2.6MB @0
    __hip_bfloat16* Mb    = wb;
    __hip_bfloat16* Wqkv  = wb + 262144;       // Wq|Wk|Wv contiguous (1536x512)
    __hip_bfloat16* Wob   = wb + 4 * 262144;
    __hip_bfloat16* n1    = (__hip_bfloat16*)(ws + ( 3ull << 20)); // 16MB @3
    __hip_bfloat16* cat   = n1;                                    // reuse @3
    __hip_bfloat16* dense = (__hip_bfloat16*)(ws + (19ull << 20)); // 16MB @19
    float*          outf  = (float*)(ws + (19ull << 20));          // 32MB @19 (dense+q dead)
    __hip_bfloat16* qkv   = (__hip_bfloat16*)(ws + (35ull << 20)); // 48MB @35
    __hip_bfloat16* qb    = qkv;
    __hip_bfloat16* kb    = qkv + 8388608;
    __hip_bfloat16* vTb   = qkv + 16777216;

    prep_w<<<640, 256, 0, stream>>>(M, Wq, Wk, Wv, Wo, wb);
    k1_conv_gelu_ln<<<16384, 256, 0, stream>>>(ts, conv_w, conv_b, pe, g1, b1, n1);
    gemm_k<0><<<dim3(128, 4), 256, 0, stream>>>(n1, Mb, dense, ts_emb, te);
    gemm_k<5><<<dim3(128, 12), 256, 0, stream>>>(dense, Wqkv, qkv, nullptr, nullptr);
    attn4_k<<<dim3(8, 128), 256, 0, stream>>>(qb, kb, vTb, cat);
    gemm_k<3><<<dim3(128, 4), 256, 0, stream>>>(cat, Wob, outf, bo, nullptr);
    k5_res_ln<<<1024, 256, 0, stream>>>(outf, ts, conv_w, conv_b, pe, g2, b2,
                                        (float*)d_out);
}

// Round 7
// 173.437 us; speedup vs baseline: 1.2654x; 1.2654x over previous
//
#include <hip/hip_runtime.h>
#include <hip/hip_bf16.h>

#define B_ 16
#define S_ 1024
#define D_ 512
#define H_ 8
#define DH_ 64

typedef __attribute__((ext_vector_type(8))) short bf16x8;
typedef __attribute__((ext_vector_type(4))) short bf16x4;
typedef __attribute__((ext_vector_type(4))) float f32x4;
typedef __attribute__((ext_vector_type(16))) float f32x16;

__device__ __forceinline__ short f2bf(float f) {
    __hip_bfloat16 h = __float2bfloat16(f);
    return *reinterpret_cast<short*>(&h);
}
__device__ __forceinline__ unsigned pack_bf2(float lo, float hi) {
    unsigned a = (unsigned)(unsigned short)f2bf(lo);
    unsigned b = (unsigned)(unsigned short)f2bf(hi);
    return a | (b << 16);
}
__device__ __forceinline__ void gload16(const void* g, void* l) {
    __builtin_amdgcn_global_load_lds(
        (const __attribute__((address_space(1))) unsigned int*)g,
        (__attribute__((address_space(3))) unsigned int*)l, 16, 0, 0);
}

// ---------------------------------------------------------------------------
// prep_w: convert the 5 weight matrices (512x512 f32) to bf16 in ws.
// Order: M, Wq (pre-scaled by 0.125*log2e), Wk, Wv, Wo.
// ---------------------------------------------------------------------------
__global__ __launch_bounds__(256) void prep_w(
    const float* __restrict__ M, const float* __restrict__ Wq,
    const float* __restrict__ Wk, const float* __restrict__ Wv,
    const float* __restrict__ Wo, __hip_bfloat16* __restrict__ wb)
{
    const int gid = blockIdx.x * 256 + threadIdx.x;
    const int e8 = gid * 8;
    const int w = e8 >> 18;
    const int off = e8 & 262143;
    const float* src = (w == 0) ? M : (w == 1) ? Wq : (w == 2) ? Wk
                      : (w == 3) ? Wv : Wo;
    const float scale = (w == 1) ? 0.18033688011112042f : 1.0f;
    const float4 f0 = *reinterpret_cast<const float4*>(src + off);
    const float4 f1 = *reinterpret_cast<const float4*>(src + off + 4);
    union { short s[8]; bf16x8 v; } r;
    r.s[0] = f2bf(f0.x * scale); r.s[1] = f2bf(f0.y * scale);
    r.s[2] = f2bf(f0.z * scale); r.s[3] = f2bf(f0.w * scale);
    r.s[4] = f2bf(f1.x * scale); r.s[5] = f2bf(f1.y * scale);
    r.s[6] = f2bf(f1.z * scale); r.s[7] = f2bf(f1.w * scale);
    *reinterpret_cast<bf16x8*>(wb + e8) = r.v;
}

// ---------------------------------------------------------------------------
// K1: conv1d + bias + pos-emb + GELU + LayerNorm over D -> n1 bf16 (B*S,512).
// One row per WAVE: 64 lanes x 8 d-elems, wave-local shfl reduce, 16B store.
// ---------------------------------------------------------------------------
__global__ __launch_bounds__(256) void k1_conv_gelu_ln(
    const float* __restrict__ ts, const float* __restrict__ conv_w,
    const float* __restrict__ conv_b, const float* __restrict__ pe,
    const float* __restrict__ g1, const float* __restrict__ b1,
    __hip_bfloat16* __restrict__ n1)
{
    const int w = threadIdx.x >> 6, lane = threadIdx.x & 63;
    const int row = blockIdx.x * 4 + w;      // b*S + s
    const int b = row >> 10, s = row & 1023;
    const float4 x = *reinterpret_cast<const float4*>(ts + b * 4096 + s * 4);
    const int d0 = lane * 8;

    const float4 cb0 = *reinterpret_cast<const float4*>(conv_b + d0);
    const float4 cb1 = *reinterpret_cast<const float4*>(conv_b + d0 + 4);
    const float4 pe0 = *reinterpret_cast<const float4*>(pe + s * 512 + d0);
    const float4 pe1 = *reinterpret_cast<const float4*>(pe + s * 512 + d0 + 4);
    const float cbv[8] = {cb0.x, cb0.y, cb0.z, cb0.w, cb1.x, cb1.y, cb1.z, cb1.w};
    const float pev[8] = {pe0.x, pe0.y, pe0.z, pe0.w, pe1.x, pe1.y, pe1.z, pe1.w};

    float a[8];
    float sum = 0.f, sq = 0.f;
#pragma unroll
    for (int j = 0; j < 8; ++j) {
        const float4 wv = *reinterpret_cast<const float4*>(conv_w + (d0 + j) * 4);
        float v = x.x * wv.x + x.y * wv.y + x.z * wv.z + x.w * wv.w
                + cbv[j] + pev[j];
        v = 0.5f * v * (1.0f + erff(v * 0.70710678118654752f));
        a[j] = v; sum += v; sq += v * v;
    }
#pragma unroll
    for (int off = 1; off < 64; off <<= 1) {
        sum += __shfl_xor(sum, off);
        sq  += __shfl_xor(sq, off);
    }
    const float mean = sum * (1.0f / 512.0f);
    const float var  = (sq - 512.0f * mean * mean) * (1.0f / 511.0f);
    const float rstd = rsqrtf(var + 1e-5f);
    const float gg = g1[s], bb = b1[s];
    union { short sh[8]; bf16x8 v; } o;
#pragma unroll
    for (int j = 0; j < 8; ++j)
        o.sh[j] = f2bf(gg * ((a[j] - mean) * rstd) + bb);
    *reinterpret_cast<bf16x8*>(n1 + (size_t)row * 512 + d0) = o.v;
}

// ---------------------------------------------------------------------------
// GEMM: out[r][n] = sum_d A[r][d] * Wb[n][d]  (A bf16 16384x512, Wb bf16 512x512)
// BM=128 BN=128 BK=64, 4 waves (2x2). global_load_lds staging, swizzled.
// MODE 0: += ts_emb[te[b]][n], bf16 row-major; MODE 1: (B,H,S,DH);
// MODE 2: (B,H,DH,S); MODE 3: += bo[n], f32 row-major
// ---------------------------------------------------------------------------
template<int MODE>
__global__ __launch_bounds__(256) void gemm_k(
    const __hip_bfloat16* __restrict__ A,
    const __hip_bfloat16* __restrict__ Wb,
    void* __restrict__ outp,
    const float* __restrict__ aux,
    const int* __restrict__ te)
{
    __shared__ char lA[128 * 128];
    __shared__ char lB[128 * 128];

    const int t = threadIdx.x;
    const int lane = t & 63;
    const int w = t >> 6;
    const int wm = w & 1, wn = w >> 1;
    const int Rb = blockIdx.x * 128;
    const int Nb = blockIdx.y * 128;
    const int g = lane >> 4, lr = lane & 15;
    const int lrow = lane >> 3;
    const int coff = ((lane & 7) ^ lrow) * 8;

    f32x4 acc[4][4];
#pragma unroll
    for (int i = 0; i < 4; ++i)
#pragma unroll
        for (int j = 0; j < 4; ++j) acc[i][j] = {0.f, 0.f, 0.f, 0.f};

    for (int kt = 0; kt < 8; ++kt) {
        const int k0 = kt * 64;
#pragma unroll
        for (int i = 0; i < 4; ++i) {
            const int r0 = w * 32 + i * 8;
            gload16(A + (size_t)(Rb + r0 + lrow) * 512 + k0 + coff, lA + r0 * 128);
        }
#pragma unroll
        for (int i = 0; i < 4; ++i) {
            const int r0 = w * 32 + i * 8;
            gload16(Wb + (size_t)(Nb + r0 + lrow) * 512 + k0 + coff, lB + r0 * 128);
        }
        __syncthreads();
#pragma unroll
        for (int kk = 0; kk < 2; ++kk) {
            bf16x8 af[4], bfv[4];
            const int ch = kk * 4 + g;
#pragma unroll
            for (int mt = 0; mt < 4; ++mt) {
                const int row = wm * 64 + mt * 16 + lr;
                af[mt] = *reinterpret_cast<const bf16x8*>(
                    lA + row * 128 + ((ch ^ (row & 7)) << 4));
            }
#pragma unroll
            for (int nt = 0; nt < 4; ++nt) {
                const int row = wn * 64 + nt * 16 + lr;
                bfv[nt] = *reinterpret_cast<const bf16x8*>(
                    lB + row * 128 + ((ch ^ (row & 7)) << 4));
            }
#pragma unroll
            for (int mt = 0; mt < 4; ++mt)
#pragma unroll
                for (int nt = 0; nt < 4; ++nt)
                    acc[mt][nt] = __builtin_amdgcn_mfma_f32_16x16x32_bf16(
                        af[mt], bfv[nt], acc[mt][nt], 0, 0, 0);
        }
        __syncthreads();
    }

#pragma unroll
    for (int mt = 0; mt < 4; ++mt) {
#pragma unroll
        for (int nt = 0; nt < 4; ++nt) {
#pragma unroll
            for (int r = 0; r < 4; ++r) {
                const int R = Rb + wm * 64 + mt * 16 + 4 * g + r;
                const int N = Nb + wn * 64 + nt * 16 + lr;
                float v = acc[mt][nt][r];
                if (MODE == 0) {
                    const int b = R >> 10;
                    v += aux[(size_t)te[b] * 512 + N];
                    reinterpret_cast<__hip_bfloat16*>(outp)[(size_t)R * 512 + N] =
                        __float2bfloat16(v);
                } else if (MODE == 1) {
                    const int b = R >> 10, s = R & 1023, h = N >> 6, c = N & 63;
                    reinterpret_cast<__hip_bfloat16*>(outp)
                        [(((size_t)(b * 8 + h)) * 1024 + s) * 64 + c] = __float2bfloat16(v);
                } else if (MODE == 2) {
                    const int b = R >> 10, s = R & 1023, h = N >> 6, c = N & 63;
                    reinterpret_cast<__hip_bfloat16*>(outp)
                        [(((size_t)(b * 8 + h)) * 64 + c) * 1024 + s] = __float2bfloat16(v);
                } else {
                    reinterpret_cast<float*>(outp)[(size_t)R * 512 + N] = v + aux[N];
                }
            }
        }
    }
}

// ---------------------------------------------------------------------------
// Flash attention: block = (bh, 128-j tile), 4 waves x 32-j strips.
// All waves share each i-tile's Q (4KB) + V (4KB), staged once per block in
// LDS via global_load_lds (pre-swizzled source, linear dest, swizzled read).
// T3 minimal 2-phase: stage(t+1) -> compute(t) -> barrier. K in registers.
// Softmax: transposed-score 32x32, in-lane, exp2 domain (Q pre-scaled),
// defer-max (T13); PV via verified permuted-k mapping.
// Grid: 1024 blocks 1D; id = slot*128 + bh (same-bh blocks share an XCD);
// jb = perm[slot] balances per-CU resident work.
// ---------------------------------------------------------------------------
__device__ __forceinline__ void write_strip(
    __hip_bfloat16* __restrict__ dstbase, const int jw0,
    const f32x16& o0, const f32x16& o1, const float lsum,
    const int l5, const int ln31)
{
    const float linv = 1.0f / lsum;
#pragma unroll
    for (int r = 0; r < 16; ++r) {
        const int jrow = (r & 3) + 8 * (r >> 2) + 4 * l5;
        const float rinv = __shfl(linv, jrow);
        __hip_bfloat16* dst = dstbase + (size_t)(jw0 + jrow) * 512;
        dst[ln31]      = __float2bfloat16(o0[r] * rinv);
        dst[32 + ln31] = __float2bfloat16(o1[r] * rinv);
    }
}

__global__ __launch_bounds__(256, 4) void attn5_k(
    const __hip_bfloat16* __restrict__ Qm,   // (B,H,S,64), pre-scaled
    const __hip_bfloat16* __restrict__ Km,   // (B,H,S,64)
    const __hip_bfloat16* __restrict__ Vt,   // (B,H,64,S)
    __hip_bfloat16* __restrict__ cat)        // (B,S,512)
{
    __shared__ char qbuf[2][4096];   // [buf][32 i-rows][128B], 16B-chunk swizzled
    __shared__ char vbuf[2][4096];   // [buf][64 d-rows][64B], 16B-chunk swizzled

    const int t = threadIdx.x, lane = t & 63, w = t >> 6;
    const int l5 = lane >> 5, ln31 = lane & 31;
    const int id = blockIdx.x;
    const int bh = id & 127;
    const int jb = (0x32451067u >> ((id >> 7) * 4)) & 7;  // perm {7,6,0,1,5,4,2,3}
    const int b = bh >> 3, h = bh & 7;
    const int j0 = jb * 128 + w * 32;

    const __hip_bfloat16* Qh = Qm + (size_t)bh * (S_ * 64);
    const __hip_bfloat16* Kh = Km + (size_t)bh * (S_ * 64);
    const __hip_bfloat16* Vh = Vt + (size_t)bh * (64 * S_);

    // K fragments for this wave's 32 j-rows (stay in registers)
    bf16x8 kf[4];
#pragma unroll
    for (int kt = 0; kt < 4; ++kt)
        kf[kt] = *reinterpret_cast<const bf16x8*>(
            Kh + (size_t)(j0 + ln31) * 64 + kt * 16 + l5 * 8);

    f32x16 o0, o1;
#pragma unroll
    for (int r = 0; r < 16; ++r) { o0[r] = 0.f; o1[r] = 0.f; }
    float m = -3e38f, lsum = 0.f;

    const int last = jb * 4 + w;         // this wave's last active tile
    const int ntiles = jb * 4 + 4;

    // staging constants (per-thread, loop-invariant)
    const int q_row  = w * 8 + (lane >> 3);
    const int q_ch   = (lane & 7) ^ (lane >> 3);
    const int v_row  = w * 16 + (lane >> 2);
    const int v_ch   = (lane & 3) ^ ((lane >> 2) & 3) ^ ((lane >> 4) & 3);
    const __hip_bfloat16* qsrc = Qh + (size_t)q_row * 64 + q_ch * 8;
    const __hip_bfloat16* vsrc = Vh + (size_t)v_row * 1024 + v_ch * 8;

    auto stage = [&](int buf, int tile) {
        const int i0 = tile * 32;
        gload16(qsrc + (size_t)i0 * 64, &qbuf[buf][w * 1024]);
        gload16(vsrc + i0,              &vbuf[buf][w * 1024]);
    };

    stage(0, 0);
    __syncthreads();

    for (int tt = 0; tt < ntiles; ++tt) {
        const int buf = tt & 1;
        if (tt + 1 < ntiles) stage(buf ^ 1, tt + 1);
        if (tt <= last) {
            // ---- QK^T from LDS ----
            f32x16 sc;
#pragma unroll
            for (int r = 0; r < 16; ++r) sc[r] = 0.f;
            bf16x8 qf[4];
#pragma unroll
            for (int kt = 0; kt < 4; ++kt)
                qf[kt] = *reinterpret_cast<const bf16x8*>(
                    &qbuf[buf][ln31 * 128 + (((kt * 2 + l5) ^ (ln31 & 7)) << 4)]);
#pragma unroll
            for (int kt = 0; kt < 4; ++kt)
                sc = __builtin_amdgcn_mfma_f32_32x32x16_bf16(qf[kt], kf[kt], sc, 0, 0, 0);

            // ---- V fragments from LDS (issue early, consumed after softmax)
            union u8 { bf16x4 h[2]; bf16x8 v; };
            u8 vf[2][2];    // [kt][drow-half]
#pragma unroll
            for (int kt = 0; kt < 2; ++kt) {
#pragma unroll
                for (int dh = 0; dh < 2; ++dh) {
                    const int drow = ln31 + dh * 32;
                    const int swz = (drow & 3) ^ ((drow >> 2) & 3);
                    const int x0 = kt * 32 + 8 * l5;
#pragma unroll
                    for (int hp = 0; hp < 2; ++hp) {
                        const int x = x0 + hp * 16;
                        vf[kt][dh].h[hp] = *reinterpret_cast<const bf16x4*>(
                            &vbuf[buf][drow * 64 + (((x >> 4) ^ swz) << 4) + (x & 15)]);
                    }
                }
            }

            // ---- mask + max + defer-max + exp + sum (exp2 domain) ----
            const bool diag = (tt == last);
            float p[16];
            float mx = -3e38f;
            if (diag) {
#pragma unroll
                for (int r = 0; r < 16; ++r) {
                    const int irow = (r & 3) + 8 * (r >> 2) + 4 * l5;
                    const float v = (irow > ln31) ? -3e38f : sc[r];
                    p[r] = v; mx = fmaxf(mx, v);
                }
            } else {
#pragma unroll
                for (int r = 0; r < 16; ++r) { p[r] = sc[r]; mx = fmaxf(mx, sc[r]); }
            }
            mx = fmaxf(mx, __shfl_xor(mx, 32));
            if (!__all(mx <= m + 8.0f)) {
                const float mn = fmaxf(m, mx);
                const float alpha = exp2f(m - mn);
                m = mn; lsum *= alpha;
#pragma unroll
                for (int r = 0; r < 16; ++r) {
                    const int jrow = (r & 3) + 8 * (r >> 2) + 4 * l5;
                    const float ar = __shfl(alpha, jrow);
                    o0[r] *= ar; o1[r] *= ar;
                }
            }
            float ps = 0.f;
#pragma unroll
            for (int r = 0; r < 16; ++r) { p[r] = exp2f(p[r] - m); ps += p[r]; }
            ps += __shfl_xor(ps, 32);
            lsum += ps;

            // ---- P pack (in-lane, permuted k) + PV ----
            union { unsigned u[4]; bf16x8 v; } pa0, pa1;
            pa0.u[0] = pack_bf2(p[0],  p[1]);  pa0.u[1] = pack_bf2(p[2],  p[3]);
            pa0.u[2] = pack_bf2(p[4],  p[5]);  pa0.u[3] = pack_bf2(p[6],  p[7]);
            pa1.u[0] = pack_bf2(p[8],  p[9]);  pa1.u[1] = pack_bf2(p[10], p[11]);
            pa1.u[2] = pack_bf2(p[12], p[13]); pa1.u[3] = pack_bf2(p[14], p[15]);
            o0 = __builtin_amdgcn_mfma_f32_32x32x16_bf16(pa0.v, vf[0][0].v, o0, 0, 0, 0);
            o1 = __builtin_amdgcn_mfma_f32_32x32x16_bf16(pa0.v, vf[0][1].v, o1, 0, 0, 0);
            o0 = __builtin_amdgcn_mfma_f32_32x32x16_bf16(pa1.v, vf[1][0].v, o0, 0, 0, 0);
            o1 = __builtin_amdgcn_mfma_f32_32x32x16_bf16(pa1.v, vf[1][1].v, o1, 0, 0, 0);
        }
        __syncthreads();
    }

    __hip_bfloat16* dstbase = cat + (size_t)b * 1024 * 512 + h * 64;
    write_strip(dstbase, j0, o0, o1, lsum, l5, ln31);
}

// ---------------------------------------------------------------------------
// K5: residual (recompute conv) + LayerNorm over D, transposed store.
// ---------------------------------------------------------------------------
__global__ __launch_bounds__(256) void k5_res_ln(
    const float* __restrict__ outf,
    const float* __restrict__ ts, const float* __restrict__ conv_w,
    const float* __restrict__ conv_b, const float* __restrict__ pe,
    const float* __restrict__ g2, const float* __restrict__ b2,
    float* __restrict__ out)         // (B,512,1024)
{
    __shared__ float tile[16 * 520];
    const int blk = blockIdx.x;
    const int b = blk >> 6, s0 = (blk & 63) * 16;
    const int t = threadIdx.x;
    const int sl = t >> 4, c = t & 15;
    const int s = s0 + sl;

    const float4 x = *reinterpret_cast<const float4*>(ts + b * 4096 + s * 4);
    float vals[32];
    float sum = 0.f, sq = 0.f;
#pragma unroll
    for (int j = 0; j < 32; ++j) {
        const int d = c + 16 * j;
        const float4 wv = *reinterpret_cast<const float4*>(conv_w + d * 4);
        const float conv = x.x * wv.x + x.y * wv.y + x.z * wv.z + x.w * wv.w
                         + conv_b[d] + pe[s * 512 + d];
        const float a = outf[(size_t)(b * 1024 + s) * 512 + d] + conv;
        vals[j] = a; sum += a; sq += a * a;
    }
#pragma unroll
    for (int off = 1; off < 16; off <<= 1) {
        sum += __shfl_xor(sum, off);
        sq  += __shfl_xor(sq, off);
    }
    const float mean = sum * (1.0f / 512.0f);
    const float var  = (sq - 512.0f * mean * mean) * (1.0f / 511.0f);
    const float rstd = rsqrtf(var + 1e-5f);
    const float gg = g2[s], bb = b2[s];
#pragma unroll
    for (int j = 0; j < 32; ++j) {
        const int d = c + 16 * j;
        tile[sl * 520 + d] = gg * ((vals[j] - mean) * rstd) + bb;
    }
    __syncthreads();
#pragma unroll
    for (int q2 = 0; q2 < 2; ++q2) {
        const int d = t + q2 * 256;
        float buf[16];
#pragma unroll
        for (int sl2 = 0; sl2 < 16; ++sl2) buf[sl2] = tile[sl2 * 520 + d];
        float4* dst = reinterpret_cast<float4*>(
            out + ((size_t)b * 512 + d) * 1024 + s0);
        dst[0] = make_float4(buf[0],  buf[1],  buf[2],  buf[3]);
        dst[1] = make_float4(buf[4],  buf[5],  buf[6],  buf[7]);
        dst[2] = make_float4(buf[8],  buf[9],  buf[10], buf[11]);
        dst[3] = make_float4(buf[12], buf[13], buf[14], buf[15]);
    }
}

// ---------------------------------------------------------------------------
extern "C" void kernel_launch(void* const* d_in, const int* in_sizes, int n_in,
                              void* d_out, int out_size, void* d_ws, size_t ws_size,
                              hipStream_t stream)
{
    const float* ts     = (const float*)d_in[0];
    const int*   te     = (const int*)d_in[1];
    const float* conv_w = (const float*)d_in[2];
    const float* conv_b = (const float*)d_in[3];
    const float* pe     = (const float*)d_in[4];
    const float* ts_emb = (const float*)d_in[5];
    const float* g1     = (const float*)d_in[6];
    const float* b1     = (const float*)d_in[7];
    const float* M      = (const float*)d_in[8];
    const float* Wq     = (const float*)d_in[9];
    const float* Wk     = (const float*)d_in[10];
    const float* Wv     = (const float*)d_in[11];
    const float* Wo     = (const float*)d_in[12];
    const float* bo     = (const float*)d_in[13];
    const float* g2     = (const float*)d_in[14];
    const float* b2     = (const float*)d_in[15];

    char* ws = (char*)d_ws;
    __hip_bfloat16* wb    = (__hip_bfloat16*)(ws);                 // 2.5MB @0
    __hip_bfloat16* Mb    = wb;
    __hip_bfloat16* Wqb   = wb + 262144;
    __hip_bfloat16* Wkb   = wb + 2 * 262144;
    __hip_bfloat16* Wvb   = wb + 3 * 262144;
    __hip_bfloat16* Wob   = wb + 4 * 262144;
    __hip_bfloat16* n1    = (__hip_bfloat16*)(ws + ( 3ull << 20)); // 16MB @3
    __hip_bfloat16* cat   = n1;                                    // reuse @3
    __hip_bfloat16* dense = (__hip_bfloat16*)(ws + (19ull << 20)); // 16MB @19
    float*          outf  = (float*)(ws + (19ull << 20));          // 32MB @19
    __hip_bfloat16* q     = (__hip_bfloat16*)(ws + (35ull << 20)); // 16MB @35
    __hip_bfloat16* k     = (__hip_bfloat16*)(ws + (51ull << 20)); // 16MB @51
    __hip_bfloat16* vT    = (__hip_bfloat16*)(ws + (67ull << 20)); // 16MB @67

    prep_w<<<640, 256, 0, stream>>>(M, Wq, Wk, Wv, Wo, wb);
    k1_conv_gelu_ln<<<4096, 256, 0, stream>>>(ts, conv_w, conv_b, pe, g1, b1, n1);
    gemm_k<0><<<dim3(128, 4), 256, 0, stream>>>(n1, Mb, dense, ts_emb, te);
    gemm_k<1><<<dim3(128, 4), 256, 0, stream>>>(dense, Wqb, q, nullptr, nullptr);
    gemm_k<1><<<dim3(128, 4), 256, 0, stream>>>(dense, Wkb, k, nullptr, nullptr);
    gemm_k<2><<<dim3(128, 4), 256, 0, stream>>>(dense, Wvb, vT, nullptr, nullptr);
    attn5_k<<<1024, 256, 0, stream>>>(q, k, vT, cat);
    gemm_k<3><<<dim3(128, 4), 256, 0, stream>>>(cat, Wob, outf, bo, nullptr);
    k5_res_ln<<<1024, 256, 0, stream>>>(outf, ts, conv_w, conv_b, pe, g2, b2,
                                        (float*)d_out);
}